// Round 18
// baseline (28.419 us; speedup 1.0000x reference)
//
#include <hip/hip_runtime.h>

namespace {

constexpr int IMGSZ = 224;
constexpr int IMG2  = IMGSZ * IMGSZ;   // 50176

// Champion (25.5us: coalesced lane map + heavy-first + (128,4)) with ONE
// change: PAIR-WIDENED column loop. Each lane handles cb pairs (2q, 2q+1),
// q = seg, seg+8, ... (so each lane reads a contiguous 32B, each 4-lane
// group a contiguous 128B - coalescing preserved), issuing all 6 channel
// loads before consuming either half. G=135 trips drop 5 -> 3. Retest of
// R10's widening now that (128,4) provides VGPR headroom (R10 ran under the
// 85-reg cap and likely spilled).
// One block = (b, 16-row chunk of one glimpse). Per WAVE (2 waves/block, no
// __syncthreads anywhere): row = lane>>2, seg = wv*4 + (lane&3).
// H[row][ox] = sum_c S[row][c]*v[c-ox] via compile-time register window
// against an LDS v-table pre-shifted by sh = col0 & 3. Reduce 4 segs (shfl
// {2,1}) -> per-wave H in LDS -> per-wave vertical partial -> atomicAdd.
// k = u v^T (rank-1 bicubic): u[r] = k[r][c0], v[c] = k[c0][c] / k[c0][c0].
// Out-of-crop columns contribute 0 via the zero-padded v-table (vpad2 reads
// reach float idx 4*(NCB2+3)+3 = 155 < 176 for G=135).
template <int G>
__device__ void chunk_glimpse(
    int b, int gi, int ch,
    const float* __restrict__ img, const int* __restrict__ locs,
    const float* __restrict__ kptr, float* __restrict__ out,
    float* __restrict__ vpad2, float* __restrict__ upad,
    float (*__restrict__ h_lds)[12]) {
  constexpr int KSZ  = G - 11;
  constexpr int C0   = KSZ / 2;
  constexpr int NCB2 = (G + 2) / 4 + 1;    // aligned 4-col blocks (covers sh<=3)
  const int lane = threadIdx.x & 63;
  const int r0 = ch * 16;

  const int x = locs[2 * b];
  const int y = locs[2 * b + 1];
  const int row0 = x - G / 2 + r0;
  const int col0 = y - G / 2;
  const int sh = col0 & 3;                 // floor-mod 4 (works for negative)
  const int col_a0 = col0 - sh;            // image-aligned start (16B aligned)
  const int R = (G - r0) < 16 ? (G - r0) : 16;
  const float* imgb = img + (size_t)b * (3 * IMG2);

  // per-wave v table: vpad2[i] = v[i - 11 - sh], zeros outside [0,KSZ)
  {
    const float rpiv = 1.0f / kptr[C0 * KSZ + C0];
    for (int i = lane; i < 176; i += 64) {
      const int k = i - 11 - sh;
      vpad2[i] = (k >= 0 && k < KSZ) ? kptr[C0 * KSZ + k] * rpiv : 0.f;
    }
  }
  // per-wave u table: upad[16+j] = u[j], zeros outside
  for (int i = lane; i < 160; i += 64) {
    const int j = i - 16;
    upad[i] = (j >= 0 && j < KSZ) ? kptr[j * KSZ + C0] : 0.f;
  }

  const int row = lane >> 2;                            // 0..15
  const int seg = (threadIdx.x >> 6) * 4 + (lane & 3);  // 0..7

  float acc[12];
  #pragma unroll
  for (int i = 0; i < 12; ++i) acc[i] = 0.f;

  const int grow = row0 + row;
  if (row < R && (unsigned)grow < (unsigned)IMGSZ) {
    const float* prow = imgb + grow * IMGSZ;
    const int cend = col0 + G;
    for (int q = seg; 2 * q < NCB2; q += 8) {
      const int cb0 = 2 * q;
      const int cb1 = 2 * q + 1;
      const int cbase0 = col_a0 + 4 * cb0;
      if (cbase0 >= cend) break;
      const int cbase1 = cbase0 + 4;
      // ---- issue all 6 loads for both halves, then consume ----
      float sj0[4], sj1[4];
      {
        const bool ok0 = (cbase0 >= 0) && (cbase0 <= IMGSZ - 4);
        const bool ok1 = (cbase1 >= 0) && (cbase1 <= IMGSZ - 4);
        if (ok0 && ok1) {
          const float4 a0 = *reinterpret_cast<const float4*>(prow + cbase0);
          const float4 b0 = *reinterpret_cast<const float4*>(prow + IMG2 + cbase0);
          const float4 c0 = *reinterpret_cast<const float4*>(prow + 2 * IMG2 + cbase0);
          const float4 a1 = *reinterpret_cast<const float4*>(prow + cbase1);
          const float4 b1 = *reinterpret_cast<const float4*>(prow + IMG2 + cbase1);
          const float4 c1 = *reinterpret_cast<const float4*>(prow + 2 * IMG2 + cbase1);
          sj0[0] = a0.x + b0.x + c0.x;
          sj0[1] = a0.y + b0.y + c0.y;
          sj0[2] = a0.z + b0.z + c0.z;
          sj0[3] = a0.w + b0.w + c0.w;
          sj1[0] = a1.x + b1.x + c1.x;
          sj1[1] = a1.y + b1.y + c1.y;
          sj1[2] = a1.z + b1.z + c1.z;
          sj1[3] = a1.w + b1.w + c1.w;
        } else {
          // edge: clamped-address scalar loads + select-0 (branchless)
          #pragma unroll
          for (int j = 0; j < 8; ++j) {
            const int cc = cbase0 + j;
            const int ccl = cc < 0 ? 0 : (cc > IMGSZ - 1 ? IMGSZ - 1 : cc);
            const float s = prow[ccl] + prow[IMG2 + ccl] + prow[2 * IMG2 + ccl];
            const float sv = ((unsigned)cc < (unsigned)IMGSZ) ? s : 0.f;
            if (j < 4) sj0[j] = sv; else sj1[j - 4] = sv;
          }
        }
      }
      // ---- half 0 ----
      {
        float vv[16];
        const float4* vt4 = reinterpret_cast<const float4*>(vpad2);
        const float4 v0 = vt4[cb0 + 0];
        const float4 v1 = vt4[cb0 + 1];
        const float4 v2 = vt4[cb0 + 2];
        const float4 v3 = vt4[cb0 + 3];
        vv[0]=v0.x; vv[1]=v0.y; vv[2]=v0.z; vv[3]=v0.w;
        vv[4]=v1.x; vv[5]=v1.y; vv[6]=v1.z; vv[7]=v1.w;
        vv[8]=v2.x; vv[9]=v2.y; vv[10]=v2.z; vv[11]=v2.w;
        vv[12]=v3.x; vv[13]=v3.y; vv[14]=v3.z; vv[15]=v3.w;
        #pragma unroll
        for (int j = 0; j < 4; ++j) {
          #pragma unroll
          for (int ox = 0; ox < 12; ++ox) {
            acc[ox] += sj0[j] * vv[11 + j - ox];
          }
        }
      }
      // ---- half 1 ----
      {
        float vv[16];
        const float4* vt4 = reinterpret_cast<const float4*>(vpad2);
        const float4 v0 = vt4[cb1 + 0];
        const float4 v1 = vt4[cb1 + 1];
        const float4 v2 = vt4[cb1 + 2];
        const float4 v3 = vt4[cb1 + 3];
        vv[0]=v0.x; vv[1]=v0.y; vv[2]=v0.z; vv[3]=v0.w;
        vv[4]=v1.x; vv[5]=v1.y; vv[6]=v1.z; vv[7]=v1.w;
        vv[8]=v2.x; vv[9]=v2.y; vv[10]=v2.z; vv[11]=v2.w;
        vv[12]=v3.x; vv[13]=v3.y; vv[14]=v3.z; vv[15]=v3.w;
        #pragma unroll
        for (int j = 0; j < 4; ++j) {
          #pragma unroll
          for (int ox = 0; ox < 12; ++ox) {
            acc[ox] += sj1[j] * vv[11 + j - ox];
          }
        }
      }
    }
  }

  // reduce 4 segs within each 4-lane group (segs at lane strides of 1)
  #pragma unroll
  for (int ox = 0; ox < 12; ++ox) {
    acc[ox] += __shfl_down(acc[ox], 2, 64);
    acc[ox] += __shfl_down(acc[ox], 1, 64);
  }
  if ((lane & 3) == 0) {
    #pragma unroll
    for (int ox = 0; ox < 12; ++ox) h_lds[lane >> 2][ox] = acc[ox];
  }
  // same-wave LDS write->read: ordered by hardware waitcnt, no barrier needed

  // per-wave vertical partial -> atomic scatter
  float* outp = out + ((size_t)b * 4 + gi) * 144;
  for (int e = lane; e < 144; e += 64) {
    const int oy = e / 12;
    const int ox = e - oy * 12;
    float s = 0.f;
    #pragma unroll
    for (int r = 0; r < 16; ++r) {
      s += upad[16 + r0 + r - oy] * h_lds[r][ox];
    }
    atomicAdd(&outp[e], s);
  }
}

__global__ __launch_bounds__(128, 4) void glimpse_kernel(
    const float* __restrict__ img, const int* __restrict__ locs,
    const float* __restrict__ k0, const float* __restrict__ k1,
    const float* __restrict__ k2, const float* __restrict__ k3,
    float* __restrict__ out) {
  __shared__ __align__(16) float vpad2[2][176];
  __shared__ __align__(16) float upad[2][160];
  __shared__ float h_lds[2][16][12];
  const int bid = blockIdx.x;
  const int b = bid & 255;
  const int t = 16 - (bid >> 8);     // heavy-first: G=135 chunks dispatch first
  const int wv = threadIdx.x >> 6;
  if (t == 0) {
    chunk_glimpse<12 >(b, 0, 0,     img, locs, k0, out, vpad2[wv], upad[wv], h_lds[wv]);
  } else if (t < 3) {
    chunk_glimpse<23 >(b, 1, t - 1, img, locs, k1, out, vpad2[wv], upad[wv], h_lds[wv]);
  } else if (t < 8) {
    chunk_glimpse<68 >(b, 2, t - 3, img, locs, k2, out, vpad2[wv], upad[wv], h_lds[wv]);
  } else {
    chunk_glimpse<135>(b, 3, t - 8, img, locs, k3, out, vpad2[wv], upad[wv], h_lds[wv]);
  }
}

}  // namespace

extern "C" void kernel_launch(void* const* d_in, const int* in_sizes, int n_in,
                              void* d_out, int out_size, void* d_ws, size_t ws_size,
                              hipStream_t stream) {
  const float* img  = (const float*)d_in[0];
  const int*   locs = (const int*)d_in[1];
  const float* k0   = (const float*)d_in[2];
  const float* k1   = (const float*)d_in[3];
  const float* k2   = (const float*)d_in[4];
  const float* k3   = (const float*)d_in[5];
  float* out = (float*)d_out;

  hipMemsetAsync(out, 0, (size_t)out_size * sizeof(float), stream);
  glimpse_kernel<<<256 * 17, 128, 0, stream>>>(img, locs, k0, k1, k2, k3, out);
}

// Round 19
// 26.369 us; speedup vs baseline: 1.0777x; 1.0777x over previous
//
#include <hip/hip_runtime.h>

namespace {

constexpr int IMGSZ = 224;
constexpr int IMG2  = IMGSZ * IMGSZ;   // 50176

// Champion (25.5us: coalesced lane map + heavy-first + (128,4)) with ONE
// change: G=135 chunks are COLUMN-SPLIT across 2 blocks. Half h covers
// global segments (wv*4 + (lane&3)) + 8h of a 16-segment space, cb stride
// 16 -> serial trips drop ~4.4 -> ~2.2 for the longest-pole blocks. The two
// halves' vertical partials combine via the existing atomicAdd epilogue.
// Other glimpses unchanged (SSTRIDE=8, segbase=0).
// One block = (b, chunk[, half]). Per WAVE (2 waves/block, no barriers):
// row = lane>>2; each 4-lane group reads a contiguous 64B row segment
// (coalesced image-aligned float4s, channel-summed).
// H[row][ox] = sum_c S[row][c]*v[c-ox] via compile-time register window
// against an LDS v-table pre-shifted by sh = col0 & 3. Reduce 4 segs (shfl
// {2,1}) -> per-wave H in LDS -> per-wave vertical partial -> atomicAdd.
// k = u v^T (rank-1 bicubic): u[r] = k[r][c0], v[c] = k[c0][c] / k[c0][c0].
template <int G, int SSTRIDE>
__device__ void chunk_glimpse(
    int b, int gi, int ch, int segbase,
    const float* __restrict__ img, const int* __restrict__ locs,
    const float* __restrict__ kptr, float* __restrict__ out,
    float* __restrict__ vpad2, float* __restrict__ upad,
    float (*__restrict__ h_lds)[12]) {
  constexpr int KSZ  = G - 11;
  constexpr int C0   = KSZ / 2;
  constexpr int NCB2 = (G + 2) / 4 + 1;    // aligned 4-col blocks (covers sh<=3)
  const int lane = threadIdx.x & 63;
  const int r0 = ch * 16;

  const int x = locs[2 * b];
  const int y = locs[2 * b + 1];
  const int row0 = x - G / 2 + r0;
  const int col0 = y - G / 2;
  const int sh = col0 & 3;                 // floor-mod 4 (works for negative)
  const int col_a0 = col0 - sh;            // image-aligned start (16B aligned)
  const int R = (G - r0) < 16 ? (G - r0) : 16;
  const float* imgb = img + (size_t)b * (3 * IMG2);

  // per-wave v table: vpad2[i] = v[i - 11 - sh], zeros outside [0,KSZ)
  {
    const float rpiv = 1.0f / kptr[C0 * KSZ + C0];
    for (int i = lane; i < 176; i += 64) {
      const int k = i - 11 - sh;
      vpad2[i] = (k >= 0 && k < KSZ) ? kptr[C0 * KSZ + k] * rpiv : 0.f;
    }
  }
  // per-wave u table: upad[16+j] = u[j], zeros outside
  for (int i = lane; i < 160; i += 64) {
    const int j = i - 16;
    upad[i] = (j >= 0 && j < KSZ) ? kptr[j * KSZ + C0] : 0.f;
  }

  const int row = lane >> 2;                                      // 0..15
  const int seg = segbase + (threadIdx.x >> 6) * 4 + (lane & 3);  // 0..SSTRIDE-1

  float acc[12];
  #pragma unroll
  for (int i = 0; i < 12; ++i) acc[i] = 0.f;

  const int grow = row0 + row;
  if (row < R && (unsigned)grow < (unsigned)IMGSZ) {
    const float* prow = imgb + grow * IMGSZ;
    const int cend = col0 + G;
    for (int cb = seg; cb < NCB2; cb += SSTRIDE) {
      const int cbase = col_a0 + 4 * cb;
      if (cbase >= cend) break;
      float sj[4];
      if (cbase >= 0 && cbase <= IMGSZ - 4) {
        const float4 a  = *reinterpret_cast<const float4*>(prow + cbase);
        const float4 b4 = *reinterpret_cast<const float4*>(prow + IMG2 + cbase);
        const float4 c4 = *reinterpret_cast<const float4*>(prow + 2 * IMG2 + cbase);
        sj[0] = a.x + b4.x + c4.x;
        sj[1] = a.y + b4.y + c4.y;
        sj[2] = a.z + b4.z + c4.z;
        sj[3] = a.w + b4.w + c4.w;
      } else {
        #pragma unroll
        for (int j = 0; j < 4; ++j) {
          const int cc = cbase + j;
          sj[j] = ((unsigned)cc < (unsigned)IMGSZ)
                      ? prow[cc] + prow[IMG2 + cc] + prow[2 * IMG2 + cc]
                      : 0.f;
        }
      }
      float vv[16];
      #pragma unroll
      for (int q = 0; q < 4; ++q) {
        const float4 v4 = *reinterpret_cast<const float4*>(vpad2 + 4 * cb + 4 * q);
        vv[q * 4 + 0] = v4.x; vv[q * 4 + 1] = v4.y;
        vv[q * 4 + 2] = v4.z; vv[q * 4 + 3] = v4.w;
      }
      #pragma unroll
      for (int j = 0; j < 4; ++j) {
        #pragma unroll
        for (int ox = 0; ox < 12; ++ox) {
          acc[ox] += sj[j] * vv[11 + j - ox];   // = v[c_rel - ox], c_rel = 4cb+j-sh
        }
      }
    }
  }

  // reduce 4 segs within each 4-lane group (segs at lane strides of 1;
  // association (s0+s2)+(s1+s3) matches the old {32,16} order bitwise)
  #pragma unroll
  for (int ox = 0; ox < 12; ++ox) {
    acc[ox] += __shfl_down(acc[ox], 2, 64);
    acc[ox] += __shfl_down(acc[ox], 1, 64);
  }
  if ((lane & 3) == 0) {
    #pragma unroll
    for (int ox = 0; ox < 12; ++ox) h_lds[lane >> 2][ox] = acc[ox];
  }
  // same-wave LDS write->read: ordered by hardware waitcnt, no barrier needed

  // per-wave vertical partial -> atomic scatter
  float* outp = out + ((size_t)b * 4 + gi) * 144;
  for (int e = lane; e < 144; e += 64) {
    const int oy = e / 12;
    const int ox = e - oy * 12;
    float s = 0.f;
    #pragma unroll
    for (int r = 0; r < 16; ++r) {
      s += upad[16 + r0 + r - oy] * h_lds[r][ox];
    }
    atomicAdd(&outp[e], s);
  }
}

__global__ __launch_bounds__(128, 4) void glimpse_kernel(
    const float* __restrict__ img, const int* __restrict__ locs,
    const float* __restrict__ k0, const float* __restrict__ k1,
    const float* __restrict__ k2, const float* __restrict__ k3,
    float* __restrict__ out) {
  __shared__ __align__(16) float vpad2[2][176];
  __shared__ __align__(16) float upad[2][160];
  __shared__ float h_lds[2][16][12];
  const int bid = blockIdx.x;
  const int b = bid & 255;
  const int slot = bid >> 8;         // 0..25 ; G135 halves first (heavy-first)
  const int wv = threadIdx.x >> 6;
  if (slot < 18) {
    // G=135: chunk ch = slot>>1, column-half = slot&1 (segs 8h..8h+7, stride 16)
    chunk_glimpse<135, 16>(b, 3, slot >> 1, (slot & 1) * 8,
                           img, locs, k3, out, vpad2[wv], upad[wv], h_lds[wv]);
  } else if (slot < 23) {
    chunk_glimpse<68, 8>(b, 2, slot - 18, 0,
                         img, locs, k2, out, vpad2[wv], upad[wv], h_lds[wv]);
  } else if (slot < 25) {
    chunk_glimpse<23, 8>(b, 1, slot - 23, 0,
                         img, locs, k1, out, vpad2[wv], upad[wv], h_lds[wv]);
  } else {
    chunk_glimpse<12, 8>(b, 0, 0, 0,
                         img, locs, k0, out, vpad2[wv], upad[wv], h_lds[wv]);
  }
}

}  // namespace

extern "C" void kernel_launch(void* const* d_in, const int* in_sizes, int n_in,
                              void* d_out, int out_size, void* d_ws, size_t ws_size,
                              hipStream_t stream) {
  const float* img  = (const float*)d_in[0];
  const int*   locs = (const int*)d_in[1];
  const float* k0   = (const float*)d_in[2];
  const float* k1   = (const float*)d_in[3];
  const float* k2   = (const float*)d_in[4];
  const float* k3   = (const float*)d_in[5];
  float* out = (float*)d_out;

  hipMemsetAsync(out, 0, (size_t)out_size * sizeof(float), stream);
  glimpse_kernel<<<256 * 26, 128, 0, stream>>>(img, locs, k0, k1, k2, k3, out);
}

// Round 20
// 25.199 us; speedup vs baseline: 1.1278x; 1.0464x over previous
//
#include <hip/hip_runtime.h>

namespace {

constexpr int IMGSZ = 224;
constexpr int IMG2  = IMGSZ * IMGSZ;   // 50176
// ws float layout: 16 pre-shifted v tables (gi*4+sh)*176, then 4 u tables gi*160
constexpr int UT_OFF = 16 * 176;       // 2816 floats
constexpr int WS_FLOATS = UT_OFF + 4 * 160;

// Prep (replaces the memset node): zeroes out AND materializes the tables.
//   vtab[(gi*4+sh)*176 + i] = v[i-11-sh] (0 outside [0,KSZ)), v = krow/piv
//   utab[gi*160 + 16 + j]   = u[j]       (0 outside)
__global__ __launch_bounds__(256) void prep_kernel(
    const float* __restrict__ k0, const float* __restrict__ k1,
    const float* __restrict__ k2, const float* __restrict__ k3,
    float* __restrict__ ws, float* __restrict__ out, int out4_count) {
  const int gid = blockIdx.x * 256 + threadIdx.x;
  if (gid < out4_count) {
    reinterpret_cast<float4*>(out)[gid] = make_float4(0.f, 0.f, 0.f, 0.f);
  }
  const int bid = blockIdx.x;
  if (bid < 16) {               // v table for gi = bid>>2, sh = bid&3
    const int gi = bid >> 2, sh = bid & 3;
    const float* kp = (gi == 0) ? k0 : (gi == 1) ? k1 : (gi == 2) ? k2 : k3;
    const int KSZ = (gi == 0) ? 1 : (gi == 1) ? 12 : (gi == 2) ? 57 : 124;
    const int C0 = KSZ / 2;
    const float rpiv = 1.0f / kp[C0 * KSZ + C0];
    if (threadIdx.x < 176) {
      const int k = (int)threadIdx.x - 11 - sh;
      ws[bid * 176 + threadIdx.x] =
          (k >= 0 && k < KSZ) ? kp[C0 * KSZ + k] * rpiv : 0.f;
    }
  } else if (bid < 20) {        // u table for gi = bid-16
    const int gi = bid - 16;
    const float* kp = (gi == 0) ? k0 : (gi == 1) ? k1 : (gi == 2) ? k2 : k3;
    const int KSZ = (gi == 0) ? 1 : (gi == 1) ? 12 : (gi == 2) ? 57 : 124;
    const int C0 = KSZ / 2;
    if (threadIdx.x < 160) {
      const int j = (int)threadIdx.x - 16;
      ws[UT_OFF + gi * 160 + threadIdx.x] =
          (j >= 0 && j < KSZ) ? kp[j * KSZ + C0] : 0.f;
    }
  }
}

// Champion (25.5us: coalesced lane map + heavy-first + (128,4)) with ONE
// change: the per-wave table fills are CONTIGUOUS COPIES from the prep'd ws
// tables (one float4 load + one LDS store per lane) instead of computed
// fills with scattered kptr loads. Main loop and epilogue byte-identical.
// One block = (b, 16-row chunk of one glimpse). Per WAVE (2 waves/block, no
// __syncthreads anywhere): row = lane>>2, seg = wv*4 + (lane&3); each 4-lane
// group reads a contiguous 64B row segment (coalesced image-aligned float4s,
// channel-summed). H[row][ox] = sum_c S[row][c]*v[c-ox] via compile-time
// register window against the LDS v-table (pre-shifted by sh = col0 & 3).
// Reduce 4 segs (shfl {2,1}) -> per-wave H in LDS -> per-wave vertical
// partial -> atomicAdd (<=18 per address).
// k = u v^T (rank-1 bicubic): u[r] = k[r][c0], v[c] = k[c0][c] / k[c0][c0].
template <int G>
__device__ void chunk_glimpse(
    int b, int gi, int ch,
    const float* __restrict__ img, const int* __restrict__ locs,
    const float* __restrict__ ws, float* __restrict__ out,
    float* __restrict__ vpad2, float* __restrict__ upad,
    float (*__restrict__ h_lds)[12]) {
  const int lane = threadIdx.x & 63;
  const int r0 = ch * 16;

  const int x = locs[2 * b];
  const int y = locs[2 * b + 1];
  const int row0 = x - G / 2 + r0;
  const int col0 = y - G / 2;
  const int sh = col0 & 3;                 // floor-mod 4 (works for negative)
  const int col_a0 = col0 - sh;            // image-aligned start (16B aligned)
  const int R = (G - r0) < 16 ? (G - r0) : 16;
  const float* imgb = img + (size_t)b * (3 * IMG2);

  // contiguous table copies from ws (prep'd): v = 44 float4, u = 40 float4
  if (lane < 44) {
    reinterpret_cast<float4*>(vpad2)[lane] =
        reinterpret_cast<const float4*>(ws + (gi * 4 + sh) * 176)[lane];
  }
  if (lane < 40) {
    reinterpret_cast<float4*>(upad)[lane] =
        reinterpret_cast<const float4*>(ws + UT_OFF + gi * 160)[lane];
  }

  constexpr int NCB2 = (G + 2) / 4 + 1;    // aligned 4-col blocks (covers sh<=3)
  const int row = lane >> 2;                            // 0..15
  const int seg = (threadIdx.x >> 6) * 4 + (lane & 3);  // 0..7

  float acc[12];
  #pragma unroll
  for (int i = 0; i < 12; ++i) acc[i] = 0.f;

  const int grow = row0 + row;
  if (row < R && (unsigned)grow < (unsigned)IMGSZ) {
    const float* prow = imgb + grow * IMGSZ;
    const int cend = col0 + G;
    for (int cb = seg; cb < NCB2; cb += 8) {
      const int cbase = col_a0 + 4 * cb;
      if (cbase >= cend) break;
      float sj[4];
      if (cbase >= 0 && cbase <= IMGSZ - 4) {
        const float4 a  = *reinterpret_cast<const float4*>(prow + cbase);
        const float4 b4 = *reinterpret_cast<const float4*>(prow + IMG2 + cbase);
        const float4 c4 = *reinterpret_cast<const float4*>(prow + 2 * IMG2 + cbase);
        sj[0] = a.x + b4.x + c4.x;
        sj[1] = a.y + b4.y + c4.y;
        sj[2] = a.z + b4.z + c4.z;
        sj[3] = a.w + b4.w + c4.w;
      } else {
        #pragma unroll
        for (int j = 0; j < 4; ++j) {
          const int cc = cbase + j;
          sj[j] = ((unsigned)cc < (unsigned)IMGSZ)
                      ? prow[cc] + prow[IMG2 + cc] + prow[2 * IMG2 + cc]
                      : 0.f;
        }
      }
      float vv[16];
      #pragma unroll
      for (int q = 0; q < 4; ++q) {
        const float4 v4 = *reinterpret_cast<const float4*>(vpad2 + 4 * cb + 4 * q);
        vv[q * 4 + 0] = v4.x; vv[q * 4 + 1] = v4.y;
        vv[q * 4 + 2] = v4.z; vv[q * 4 + 3] = v4.w;
      }
      #pragma unroll
      for (int j = 0; j < 4; ++j) {
        #pragma unroll
        for (int ox = 0; ox < 12; ++ox) {
          acc[ox] += sj[j] * vv[11 + j - ox];   // = v[c_rel - ox], c_rel = 4cb+j-sh
        }
      }
    }
  }

  // reduce 4 segs within each 4-lane group (segs at lane strides of 1;
  // association (s0+s2)+(s1+s3) matches the old {32,16} order bitwise)
  #pragma unroll
  for (int ox = 0; ox < 12; ++ox) {
    acc[ox] += __shfl_down(acc[ox], 2, 64);
    acc[ox] += __shfl_down(acc[ox], 1, 64);
  }
  if ((lane & 3) == 0) {
    #pragma unroll
    for (int ox = 0; ox < 12; ++ox) h_lds[lane >> 2][ox] = acc[ox];
  }
  // same-wave LDS write->read: ordered by hardware waitcnt, no barrier needed

  // per-wave vertical partial -> atomic scatter
  float* outp = out + ((size_t)b * 4 + gi) * 144;
  for (int e = lane; e < 144; e += 64) {
    const int oy = e / 12;
    const int ox = e - oy * 12;
    float s = 0.f;
    #pragma unroll
    for (int r = 0; r < 16; ++r) {
      s += upad[16 + r0 + r - oy] * h_lds[r][ox];
    }
    atomicAdd(&outp[e], s);
  }
}

__global__ __launch_bounds__(128, 4) void glimpse_kernel(
    const float* __restrict__ img, const int* __restrict__ locs,
    const float* __restrict__ ws, float* __restrict__ out) {
  __shared__ __align__(16) float vpad2[2][176];
  __shared__ __align__(16) float upad[2][160];
  __shared__ float h_lds[2][16][12];
  const int bid = blockIdx.x;
  const int b = bid & 255;
  const int t = 16 - (bid >> 8);     // heavy-first: G=135 chunks dispatch first
  const int wv = threadIdx.x >> 6;
  if (t == 0) {
    chunk_glimpse<12 >(b, 0, 0,     img, locs, ws, out, vpad2[wv], upad[wv], h_lds[wv]);
  } else if (t < 3) {
    chunk_glimpse<23 >(b, 1, t - 1, img, locs, ws, out, vpad2[wv], upad[wv], h_lds[wv]);
  } else if (t < 8) {
    chunk_glimpse<68 >(b, 2, t - 3, img, locs, ws, out, vpad2[wv], upad[wv], h_lds[wv]);
  } else {
    chunk_glimpse<135>(b, 3, t - 8, img, locs, ws, out, vpad2[wv], upad[wv], h_lds[wv]);
  }
}

}  // namespace

extern "C" void kernel_launch(void* const* d_in, const int* in_sizes, int n_in,
                              void* d_out, int out_size, void* d_ws, size_t ws_size,
                              hipStream_t stream) {
  const float* img  = (const float*)d_in[0];
  const int*   locs = (const int*)d_in[1];
  const float* k0   = (const float*)d_in[2];
  const float* k1   = (const float*)d_in[3];
  const float* k2   = (const float*)d_in[4];
  const float* k3   = (const float*)d_in[5];
  float* ws  = (float*)d_ws;
  float* out = (float*)d_out;

  const int out4_count = out_size / 4;     // out_size = 147456 floats, /4 per float4
  prep_kernel<<<256, 256, 0, stream>>>(k0, k1, k2, k3, ws, out, out4_count);
  glimpse_kernel<<<256 * 17, 128, 0, stream>>>(img, locs, ws, out);
}

// Round 21
// 23.930 us; speedup vs baseline: 1.1876x; 1.0531x over previous
//
#include <hip/hip_runtime.h>

namespace {

constexpr int IMGSZ = 224;
constexpr int IMG2  = IMGSZ * IMGSZ;   // 50176
// ws float layout: 16 pre-shifted v tables (gi*4+sh)*176, then 4 u tables gi*160
constexpr int UT_OFF = 16 * 176;       // 2816 floats

// Prep (replaces the memset node): zeroes out AND materializes the tables.
//   vtab[(gi*4+sh)*176 + i] = v[i-11-sh] (0 outside [0,KSZ)), v = krow/piv
//   utab[gi*160 + 16 + j]   = u[j]       (0 outside)
__global__ __launch_bounds__(256) void prep_kernel(
    const float* __restrict__ k0, const float* __restrict__ k1,
    const float* __restrict__ k2, const float* __restrict__ k3,
    float* __restrict__ ws, float* __restrict__ out, int out4_count) {
  const int gid = blockIdx.x * 256 + threadIdx.x;
  if (gid < out4_count) {
    reinterpret_cast<float4*>(out)[gid] = make_float4(0.f, 0.f, 0.f, 0.f);
  }
  const int bid = blockIdx.x;
  if (bid < 16) {               // v table for gi = bid>>2, sh = bid&3
    const int gi = bid >> 2, sh = bid & 3;
    const float* kp = (gi == 0) ? k0 : (gi == 1) ? k1 : (gi == 2) ? k2 : k3;
    const int KSZ = (gi == 0) ? 1 : (gi == 1) ? 12 : (gi == 2) ? 57 : 124;
    const int C0 = KSZ / 2;
    const float rpiv = 1.0f / kp[C0 * KSZ + C0];
    if (threadIdx.x < 176) {
      const int k = (int)threadIdx.x - 11 - sh;
      ws[bid * 176 + threadIdx.x] =
          (k >= 0 && k < KSZ) ? kp[C0 * KSZ + k] * rpiv : 0.f;
    }
  } else if (bid < 20) {        // u table for gi = bid-16
    const int gi = bid - 16;
    const float* kp = (gi == 0) ? k0 : (gi == 1) ? k1 : (gi == 2) ? k2 : k3;
    const int KSZ = (gi == 0) ? 1 : (gi == 1) ? 12 : (gi == 2) ? 57 : 124;
    const int C0 = KSZ / 2;
    if (threadIdx.x < 160) {
      const int j = (int)threadIdx.x - 16;
      ws[UT_OFF + gi * 160 + threadIdx.x] =
          (j >= 0 && j < KSZ) ? kp[j * KSZ + C0] : 0.f;
    }
  }
}

// Champion (25.2us: coalesced lane map + heavy-first + (128,4) + prep'd
// table copies) with ONE change: COMBINED CROSS-WAVE EPILOGUE. Both waves
// write their H partial to h_lds[wv], one __syncthreads, then 128 threads
// perform a single vertical pass over (h0[r][ox] + h1[r][ox]) -> HALF the
// atomics (144/block instead of 288) and half the vertical FMA/LDS work.
// Barrier skew bounded by <=1 trip difference between waves.
// One block = (b, 16-row chunk of one glimpse): row = lane>>2,
// seg = wv*4 + (lane&3); each 4-lane group reads a contiguous 64B row
// segment (coalesced image-aligned float4s, channel-summed). H[row][ox] =
// sum_c S[row][c]*v[c-ox] via compile-time register window against the LDS
// v-table (pre-shifted by sh = col0 & 3). Reduce 4 segs (shfl {2,1}) ->
// h_lds[wv] -> barrier -> combined vertical partial -> atomicAdd.
// k = u v^T (rank-1 bicubic): u[r] = k[r][c0], v[c] = k[c0][c] / k[c0][c0].
template <int G>
__device__ void chunk_glimpse(
    int b, int gi, int ch,
    const float* __restrict__ img, const int* __restrict__ locs,
    const float* __restrict__ ws, float* __restrict__ out,
    float* __restrict__ vpad2, float* __restrict__ upad,
    float (*__restrict__ h_lds)[16][12]) {
  const int tid = threadIdx.x;
  const int lane = tid & 63;
  const int wv = tid >> 6;
  const int r0 = ch * 16;

  const int x = locs[2 * b];
  const int y = locs[2 * b + 1];
  const int row0 = x - G / 2 + r0;
  const int col0 = y - G / 2;
  const int sh = col0 & 3;                 // floor-mod 4 (works for negative)
  const int col_a0 = col0 - sh;            // image-aligned start (16B aligned)
  const int R = (G - r0) < 16 ? (G - r0) : 16;
  const float* imgb = img + (size_t)b * (3 * IMG2);

  // contiguous table copies from ws (prep'd): v = 44 float4, u = 40 float4
  if (lane < 44) {
    reinterpret_cast<float4*>(vpad2)[lane] =
        reinterpret_cast<const float4*>(ws + (gi * 4 + sh) * 176)[lane];
  }
  if (lane < 40) {
    reinterpret_cast<float4*>(upad)[lane] =
        reinterpret_cast<const float4*>(ws + UT_OFF + gi * 160)[lane];
  }

  constexpr int NCB2 = (G + 2) / 4 + 1;    // aligned 4-col blocks (covers sh<=3)
  const int row = lane >> 2;                  // 0..15
  const int seg = wv * 4 + (lane & 3);        // 0..7

  float acc[12];
  #pragma unroll
  for (int i = 0; i < 12; ++i) acc[i] = 0.f;

  const int grow = row0 + row;
  if (row < R && (unsigned)grow < (unsigned)IMGSZ) {
    const float* prow = imgb + grow * IMGSZ;
    const int cend = col0 + G;
    for (int cb = seg; cb < NCB2; cb += 8) {
      const int cbase = col_a0 + 4 * cb;
      if (cbase >= cend) break;
      float sj[4];
      if (cbase >= 0 && cbase <= IMGSZ - 4) {
        const float4 a  = *reinterpret_cast<const float4*>(prow + cbase);
        const float4 b4 = *reinterpret_cast<const float4*>(prow + IMG2 + cbase);
        const float4 c4 = *reinterpret_cast<const float4*>(prow + 2 * IMG2 + cbase);
        sj[0] = a.x + b4.x + c4.x;
        sj[1] = a.y + b4.y + c4.y;
        sj[2] = a.z + b4.z + c4.z;
        sj[3] = a.w + b4.w + c4.w;
      } else {
        #pragma unroll
        for (int j = 0; j < 4; ++j) {
          const int cc = cbase + j;
          sj[j] = ((unsigned)cc < (unsigned)IMGSZ)
                      ? prow[cc] + prow[IMG2 + cc] + prow[2 * IMG2 + cc]
                      : 0.f;
        }
      }
      float vv[16];
      #pragma unroll
      for (int q = 0; q < 4; ++q) {
        const float4 v4 = *reinterpret_cast<const float4*>(vpad2 + 4 * cb + 4 * q);
        vv[q * 4 + 0] = v4.x; vv[q * 4 + 1] = v4.y;
        vv[q * 4 + 2] = v4.z; vv[q * 4 + 3] = v4.w;
      }
      #pragma unroll
      for (int j = 0; j < 4; ++j) {
        #pragma unroll
        for (int ox = 0; ox < 12; ++ox) {
          acc[ox] += sj[j] * vv[11 + j - ox];   // = v[c_rel - ox], c_rel = 4cb+j-sh
        }
      }
    }
  }

  // reduce 4 segs within each 4-lane group (segs at lane strides of 1;
  // association (s0+s2)+(s1+s3) matches the old {32,16} order bitwise)
  #pragma unroll
  for (int ox = 0; ox < 12; ++ox) {
    acc[ox] += __shfl_down(acc[ox], 2, 64);
    acc[ox] += __shfl_down(acc[ox], 1, 64);
  }
  if ((lane & 3) == 0) {
    #pragma unroll
    for (int ox = 0; ox < 12; ++ox) h_lds[wv][lane >> 2][ox] = acc[ox];
  }
  __syncthreads();

  // combined vertical partial over both waves' H -> one atomic per element
  float* outp = out + ((size_t)b * 4 + gi) * 144;
  for (int e = tid; e < 144; e += 128) {
    const int oy = e / 12;
    const int ox = e - oy * 12;
    float s = 0.f;
    #pragma unroll
    for (int r = 0; r < 16; ++r) {
      s += upad[16 + r0 + r - oy] * (h_lds[0][r][ox] + h_lds[1][r][ox]);
    }
    atomicAdd(&outp[e], s);
  }
}

__global__ __launch_bounds__(128, 4) void glimpse_kernel(
    const float* __restrict__ img, const int* __restrict__ locs,
    const float* __restrict__ ws, float* __restrict__ out) {
  __shared__ __align__(16) float vpad2[2][176];
  __shared__ __align__(16) float upad[2][160];
  __shared__ __align__(16) float h_lds[2][16][12];
  const int bid = blockIdx.x;
  const int b = bid & 255;
  const int t = 16 - (bid >> 8);     // heavy-first: G=135 chunks dispatch first
  const int wv = threadIdx.x >> 6;
  if (t == 0) {
    chunk_glimpse<12 >(b, 0, 0,     img, locs, ws, out, vpad2[wv], upad[wv], h_lds);
  } else if (t < 3) {
    chunk_glimpse<23 >(b, 1, t - 1, img, locs, ws, out, vpad2[wv], upad[wv], h_lds);
  } else if (t < 8) {
    chunk_glimpse<68 >(b, 2, t - 3, img, locs, ws, out, vpad2[wv], upad[wv], h_lds);
  } else {
    chunk_glimpse<135>(b, 3, t - 8, img, locs, ws, out, vpad2[wv], upad[wv], h_lds);
  }
}

}  // namespace

extern "C" void kernel_launch(void* const* d_in, const int* in_sizes, int n_in,
                              void* d_out, int out_size, void* d_ws, size_t ws_size,
                              hipStream_t stream) {
  const float* img  = (const float*)d_in[0];
  const int*   locs = (const int*)d_in[1];
  const float* k0   = (const float*)d_in[2];
  const float* k1   = (const float*)d_in[3];
  const float* k2   = (const float*)d_in[4];
  const float* k3   = (const float*)d_in[5];
  float* ws  = (float*)d_ws;
  float* out = (float*)d_out;

  const int out4_count = out_size / 4;     // out_size floats, /4 per float4
  prep_kernel<<<256, 256, 0, stream>>>(k0, k1, k2, k3, ws, out, out4_count);
  glimpse_kernel<<<256 * 17, 128, 0, stream>>>(img, locs, ws, out);
}